// Round 8
// baseline (308.083 us; speedup 1.0000x reference)
//
#include <hip/hip_runtime.h>

typedef float f32x2 __attribute__((ext_vector_type(2)));

__device__ __forceinline__ f32x2 splat2(float s) { f32x2 v; v.x = s; v.y = s; return v; }

// ---- VOP3P packed-f32 with SGPR-pair scalar broadcast via op_sel ----
// w is an SGPR pair (two consecutive weights). _l uses w.lo for both halves,
// _h uses w.hi for both halves. x, c are VGPR pairs (2 spatial points).
__device__ __forceinline__ void pk_fma_l(f32x2& c, const f32x2 w, const f32x2 x) {
    asm("v_pk_fma_f32 %0, %1, %2, %0 op_sel:[0,0,0] op_sel_hi:[0,1,1]"
        : "+v"(c) : "s"(w), "v"(x));
}
__device__ __forceinline__ void pk_fma_h(f32x2& c, const f32x2 w, const f32x2 x) {
    asm("v_pk_fma_f32 %0, %1, %2, %0 op_sel:[1,0,0] op_sel_hi:[1,1,1]"
        : "+v"(c) : "s"(w), "v"(x));
}
__device__ __forceinline__ f32x2 pk_mul_l(const f32x2 w, const f32x2 x) {
    f32x2 d;
    asm("v_pk_mul_f32 %0, %1, %2 op_sel:[0,0] op_sel_hi:[0,1]"
        : "=v"(d) : "s"(w), "v"(x));
    return d;
}
__device__ __forceinline__ f32x2 pk_add_l(const f32x2 w, const f32x2 x) {
    f32x2 d;
    asm("v_pk_add_f32 %0, %1, %2 op_sel:[0,0] op_sel_hi:[0,1]"
        : "=v"(d) : "s"(w), "v"(x));
    return d;
}
__device__ __forceinline__ f32x2 pk_add_h(const f32x2 w, const f32x2 x) {
    f32x2 d;
    asm("v_pk_add_f32 %0, %1, %2 op_sel:[1,0] op_sel_hi:[1,1]"
        : "=v"(d) : "s"(w), "v"(x));
    return d;
}
__device__ __forceinline__ f32x2 pk_add(const f32x2 a, const f32x2 b) {
    f32x2 d;
    asm("v_pk_add_f32 %0, %1, %2 op_sel:[0,0] op_sel_hi:[1,1]"
        : "=v"(d) : "v"(a), "v"(b));
    return d;
}
__device__ __forceinline__ f32x2 prelu(f32x2 a) { return __builtin_elementwise_max(a, splat2(0.0f)); }

// ---- ws layout (floats) ----
// [o*24 + 0..9]   j-MLP: w0..w5(sym: cols 0,4,6,(1+2)/2,(3+5)/2,(7+8)/2),
//                 a0..a2(anti: (1-2)/2,(3-5)/2,(7-8)/2), b1j
// [o*24 +10..19]  n-MLP same; [o*24+20] w2j [o*24+21] w2n   (o=0..23)
// [576 + r*10 + i] TM[r][i] (tv = TM @ f), row padded to 10
// [672 + r*10 + j] Minv[r][j], row padded to 10
// [764] b2j  [765] 2*b2n

__global__ __launch_bounds__(256) void prep_kernel(
    const float* __restrict__ j_w1, const float* __restrict__ j_b1,
    const float* __restrict__ j_w2, const float* __restrict__ j_b2,
    const float* __restrict__ n_w1, const float* __restrict__ n_b1,
    const float* __restrict__ n_w2, const float* __restrict__ n_b2,
    const float* __restrict__ Mg, const float* __restrict__ Minvg,
    float* __restrict__ ws)
{
    const int t = threadIdx.x;
    if (t < 48) {
        const int o = t >> 1, which = t & 1;
        const float* w1 = which ? n_w1 : j_w1;
        const float* b1 = which ? n_b1 : j_b1;
        float w[9];
        #pragma unroll
        for (int i = 0; i < 9; ++i) w[i] = w1[o * 9 + i];
        float* dst = ws + o * 24 + which * 10;
        dst[0] = w[0]; dst[1] = w[4]; dst[2] = w[6];
        dst[3] = 0.5f * (w[1] + w[2]); dst[4] = 0.5f * (w[3] + w[5]); dst[5] = 0.5f * (w[7] + w[8]);
        dst[6] = 0.5f * (w[1] - w[2]); dst[7] = 0.5f * (w[3] - w[5]); dst[8] = 0.5f * (w[7] - w[8]);
        dst[9] = b1[o];
        if (!which) {
            ws[o * 24 + 20] = j_w2[o];
            ws[o * 24 + 21] = n_w2[o];
            ws[o * 24 + 22] = 0.0f;
            ws[o * 24 + 23] = 0.0f;
        }
    } else if (t >= 64 && t < 64 + 90) {
        const int e = t - 64, r = e / 10, i = e % 10;
        float v;
        if (i == 9) v = 0.0f;
        else switch (r) {
            case 0: v = Mg[0 * 9 + i]; break;
            case 1: v = Mg[4 * 9 + i]; break;
            case 2: v = Mg[6 * 9 + i]; break;
            case 3: v = Mg[1 * 9 + i] + Mg[2 * 9 + i]; break;
            case 4: v = Mg[3 * 9 + i] + Mg[5 * 9 + i]; break;
            case 5: v = Mg[7 * 9 + i] + Mg[8 * 9 + i]; break;
            case 6: v = Mg[1 * 9 + i] - Mg[2 * 9 + i]; break;
            case 7: v = Mg[3 * 9 + i] - Mg[5 * 9 + i]; break;
            default: v = Mg[7 * 9 + i] - Mg[8 * 9 + i]; break;
        }
        ws[576 + r * 10 + i] = v;
    } else if (t >= 160 && t < 160 + 90) {
        const int e = t - 160, r = e / 10, j = e % 10;
        ws[672 + r * 10 + j] = (j == 9) ? 0.0f : Minvg[r * 9 + j];
    } else if (t == 254) {
        ws[764] = j_b2[0];
    } else if (t == 255) {
        ws[765] = 2.0f * n_b2[0];
    }
}

__global__ __launch_bounds__(256) void mrt_main(
    const float* __restrict__ f, const float* __restrict__ W,
    float* __restrict__ out, int n2)
{
    long base = ((long)blockIdx.x * 256 + threadIdx.x) * 8;
    if (base + 8 > n2) base = n2 - 8;

    // ---- phase 1: load f (8 pts = 4 pairs), tv = TM @ f ----
    f32x2 tv[4][9];
    {
        f32x2 fv[4][9];
        #pragma unroll
        for (int i = 0; i < 9; ++i) {
            const float4 u0 = *reinterpret_cast<const float4*>(f + (size_t)i * n2 + base);
            const float4 u1 = *reinterpret_cast<const float4*>(f + (size_t)i * n2 + base + 4);
            fv[0][i].x = u0.x; fv[0][i].y = u0.y;
            fv[1][i].x = u0.z; fv[1][i].y = u0.w;
            fv[2][i].x = u1.x; fv[2][i].y = u1.y;
            fv[3][i].x = u1.z; fv[3][i].y = u1.w;
        }
        #pragma unroll
        for (int r = 0; r < 9; ++r) {
            const f32x2* Tp = reinterpret_cast<const f32x2*>(W + 576 + r * 10);
            const f32x2 t0 = Tp[0], t1 = Tp[1], t2 = Tp[2], t3 = Tp[3], t4 = Tp[4];
            #pragma unroll
            for (int p = 0; p < 4; ++p) {
                f32x2 acc = pk_mul_l(t0, fv[p][0]);
                pk_fma_h(acc, t0, fv[p][1]);
                pk_fma_l(acc, t1, fv[p][2]);
                pk_fma_h(acc, t1, fv[p][3]);
                pk_fma_l(acc, t2, fv[p][4]);
                pk_fma_h(acc, t2, fv[p][5]);
                pk_fma_l(acc, t3, fv[p][6]);
                pk_fma_h(acc, t3, fv[p][7]);
                pk_fma_l(acc, t4, fv[p][8]);
                tv[p][r] = acc;
            }
        }
    }

    // ---- phase 2: fused hidden layer (j, j-flip, n+n-flip) ----
    f32x2 accj[4], accjf[4], accn[4];
    #pragma unroll
    for (int p = 0; p < 4; ++p) { accj[p] = splat2(0.f); accjf[p] = splat2(0.f); accn[p] = splat2(0.f); }

    #pragma unroll 4
    for (int o = 0; o < 24; ++o) {
        const f32x2* wp = reinterpret_cast<const f32x2*>(W + o * 24);
        const f32x2 w01 = wp[0], w23 = wp[1], w45 = wp[2], aa01 = wp[3], a2b = wp[4];
        const f32x2 u01 = wp[5], u23 = wp[6], u45 = wp[7], vv01 = wp[8], v2b = wp[9];
        const f32x2 w2p = wp[10];
        #pragma unroll
        for (int p = 0; p < 4; ++p) {
            f32x2 s = pk_mul_l(w01, tv[p][0]);
            pk_fma_h(s, w01, tv[p][1]);
            pk_fma_l(s, w23, tv[p][2]);
            pk_fma_h(s, w23, tv[p][3]);
            pk_fma_l(s, w45, tv[p][4]);
            pk_fma_h(s, w45, tv[p][5]);
            f32x2 a = pk_mul_l(aa01, tv[p][6]);
            pk_fma_h(a, aa01, tv[p][7]);
            pk_fma_l(a, a2b, tv[p][8]);
            const f32x2 hs = prelu(pk_add_h(a2b, pk_add(s, a)));   // +b1j then relu
            const f32x2 hd = prelu(pk_add_h(a2b, s - a));
            pk_fma_l(accj[p], w2p, hs);
            pk_fma_l(accjf[p], w2p, hd);

            f32x2 sn = pk_mul_l(u01, tv[p][0]);
            pk_fma_h(sn, u01, tv[p][1]);
            pk_fma_l(sn, u23, tv[p][2]);
            pk_fma_h(sn, u23, tv[p][3]);
            pk_fma_l(sn, u45, tv[p][4]);
            pk_fma_h(sn, u45, tv[p][5]);
            f32x2 an = pk_mul_l(vv01, tv[p][6]);
            pk_fma_h(an, vv01, tv[p][7]);
            pk_fma_l(an, v2b, tv[p][8]);
            const f32x2 ns = prelu(pk_add_h(v2b, pk_add(sn, an)));
            const f32x2 nd = prelu(pk_add_h(v2b, sn - an));
            pk_fma_h(accn[p], w2p, pk_add(ns, nd));
        }
    }

    // ---- phase 3: taus + m_post ----
    const f32x2 b2p = *reinterpret_cast<const f32x2*>(W + 764);   // (b2j, 2*b2n)
    const f32x2 Cs = splat2(1.0f / 0.7f);
    f32x2 mp[4][9];
    #pragma unroll
    for (int p = 0; p < 4; ++p) {
        const f32x2 aj  = pk_add_l(b2p, accj[p]);
        const f32x2 ajf = pk_add_l(b2p, accjf[p]);
        const f32x2 an  = pk_add_h(b2p, accn[p]);
        f32x2 rt7, rt8, rt6, rrho;
        rt7.x = __builtin_amdgcn_rcpf(0.5f + __expf(aj.x));
        rt7.y = __builtin_amdgcn_rcpf(0.5f + __expf(aj.y));
        rt8.x = __builtin_amdgcn_rcpf(0.5f + __expf(ajf.x));
        rt8.y = __builtin_amdgcn_rcpf(0.5f + __expf(ajf.y));
        rt6.x = __builtin_amdgcn_rcpf(0.5f + __expf(an.x));
        rt6.y = __builtin_amdgcn_rcpf(0.5f + __expf(an.y));
        rrho.x = __builtin_amdgcn_rcpf(tv[p][0].x);
        rrho.y = __builtin_amdgcn_rcpf(tv[p][0].y);

        const f32x2 jx = splat2(0.5f) * (tv[p][3] + tv[p][6]);
        const f32x2 jy = splat2(0.5f) * (tv[p][3] - tv[p][6]);
        const f32x2 m3 = splat2(0.5f) * (tv[p][4] + tv[p][7]);
        const f32x2 m5 = splat2(0.5f) * (tv[p][4] - tv[p][7]);
        const f32x2 m7 = splat2(0.5f) * (tv[p][5] + tv[p][8]);
        const f32x2 m8 = splat2(0.5f) * (tv[p][5] - tv[p][8]);
        const f32x2 m4 = tv[p][1], m6 = tv[p][2];

        mp[p][0] = tv[p][0];
        mp[p][1] = jx;
        mp[p][2] = jy;
        mp[p][3] = m3 - (m3 - jx * jx * rrho) * Cs;
        mp[p][4] = m4 - (m4 - jx * jy * rrho) * Cs;
        mp[p][5] = m5 - (m5 - jy * jy * rrho) * Cs;
        mp[p][6] = m6 - m6 * rt6;
        mp[p][7] = m7 - m7 * rt7;
        mp[p][8] = m8 - m8 * rt8;
    }

    // ---- phase 4: out = Minv @ m_post ----
    #pragma unroll
    for (int r = 0; r < 9; ++r) {
        const f32x2* Qp = reinterpret_cast<const f32x2*>(W + 672 + r * 10);
        const f32x2 q0 = Qp[0], q1 = Qp[1], q2 = Qp[2], q3 = Qp[3], q4 = Qp[4];
        f32x2 ov[4];
        #pragma unroll
        for (int p = 0; p < 4; ++p) {
            f32x2 o0 = pk_mul_l(q0, mp[p][0]);
            pk_fma_h(o0, q0, mp[p][1]);
            pk_fma_l(o0, q1, mp[p][2]);
            pk_fma_h(o0, q1, mp[p][3]);
            pk_fma_l(o0, q2, mp[p][4]);
            pk_fma_h(o0, q2, mp[p][5]);
            pk_fma_l(o0, q3, mp[p][6]);
            pk_fma_h(o0, q3, mp[p][7]);
            pk_fma_l(o0, q4, mp[p][8]);
            ov[p] = o0;
        }
        const float4 A = make_float4(ov[0].x, ov[0].y, ov[1].x, ov[1].y);
        const float4 B = make_float4(ov[2].x, ov[2].y, ov[3].x, ov[3].y);
        *reinterpret_cast<float4*>(out + (size_t)r * n2 + base)     = A;
        *reinterpret_cast<float4*>(out + (size_t)r * n2 + base + 4) = B;
    }
}

extern "C" void kernel_launch(void* const* d_in, const int* in_sizes, int n_in,
                              void* d_out, int out_size, void* d_ws, size_t ws_size,
                              hipStream_t stream) {
    const float* f    = (const float*)d_in[0];
    const float* j_w1 = (const float*)d_in[1];
    const float* j_b1 = (const float*)d_in[2];
    const float* j_w2 = (const float*)d_in[3];
    const float* j_b2 = (const float*)d_in[4];
    const float* n_w1 = (const float*)d_in[5];
    const float* n_b1 = (const float*)d_in[6];
    const float* n_w2 = (const float*)d_in[7];
    const float* n_b2 = (const float*)d_in[8];
    const float* Mg   = (const float*)d_in[9];
    const float* Minv = (const float*)d_in[10];
    float* out = (float*)d_out;
    float* ws  = (float*)d_ws;

    const int n2 = in_sizes[0] / 9;
    const int pts_per_block = 256 * 8;
    const int grid = (n2 + pts_per_block - 1) / pts_per_block;

    prep_kernel<<<1, 256, 0, stream>>>(j_w1, j_b1, j_w2, j_b2,
                                       n_w1, n_b1, n_w2, n_b2, Mg, Minv, ws);
    mrt_main<<<grid, 256, 0, stream>>>(f, ws, out, n2);
}

// Round 10
// 295.747 us; speedup vs baseline: 1.0417x; 1.0417x over previous
//
#include <hip/hip_runtime.h>

typedef _Float16 h2 __attribute__((ext_vector_type(2)));

__device__ __forceinline__ h2 h2splat(float s) {
    const _Float16 v = (_Float16)s;
    h2 r; r.x = v; r.y = v; return r;
}
__device__ __forceinline__ h2 h2fma(h2 a, h2 b, h2 c) { return __builtin_elementwise_fma(a, b, c); }
__device__ __forceinline__ h2 h2relu(h2 a) {
    h2 z; z.x = (_Float16)0.0f; z.y = (_Float16)0.0f;
    return __builtin_elementwise_max(a, z);
}

// ---- ws layout ----
// h2-duplicated weights (one dword each), index o*22 + k:
//   k=0..5  j sym (cols 0,4,6, (1+2)/2, (3+5)/2, (7+8)/2)
//   k=6..8  j anti ((1-2)/2, (3-5)/2, (7-8)/2)
//   k=9     b1j;  k=10..15 n sym; 16..18 n anti; 19 b1n; 20 w2j; 21 w2n
// floats from Wf = ws+528:
//   [r*9+i] TM[r][i];  [81 + r*9 + j] Minv[r][j];  [162] b2j;  [163] 2*b2n

__global__ __launch_bounds__(256) void prep_kernel(
    const float* __restrict__ j_w1, const float* __restrict__ j_b1,
    const float* __restrict__ j_w2, const float* __restrict__ j_b2,
    const float* __restrict__ n_w1, const float* __restrict__ n_b1,
    const float* __restrict__ n_w2, const float* __restrict__ n_b2,
    const float* __restrict__ Mg, const float* __restrict__ Minvg,
    float* __restrict__ ws)
{
    const int t = threadIdx.x;
    h2* wh = reinterpret_cast<h2*>(ws);
    if (t < 48) {
        const int o = t >> 1, which = t & 1;
        const float* w1 = which ? n_w1 : j_w1;
        const float* b1 = which ? n_b1 : j_b1;
        float w[9];
        #pragma unroll
        for (int i = 0; i < 9; ++i) w[i] = w1[o * 9 + i];
        const int b = o * 22 + which * 10;
        wh[b + 0] = h2splat(w[0]);
        wh[b + 1] = h2splat(w[4]);
        wh[b + 2] = h2splat(w[6]);
        wh[b + 3] = h2splat(0.5f * (w[1] + w[2]));
        wh[b + 4] = h2splat(0.5f * (w[3] + w[5]));
        wh[b + 5] = h2splat(0.5f * (w[7] + w[8]));
        wh[b + 6] = h2splat(0.5f * (w[1] - w[2]));
        wh[b + 7] = h2splat(0.5f * (w[3] - w[5]));
        wh[b + 8] = h2splat(0.5f * (w[7] - w[8]));
        wh[b + 9] = h2splat(b1[o]);
        if (!which) {
            wh[o * 22 + 20] = h2splat(j_w2[o]);
            wh[o * 22 + 21] = h2splat(n_w2[o]);
        }
    } else if (t >= 64 && t < 64 + 81) {
        const int e = t - 64, r = e / 9, i = e % 9;
        float v;
        switch (r) {
            case 0: v = Mg[0 * 9 + i]; break;
            case 1: v = Mg[4 * 9 + i]; break;
            case 2: v = Mg[6 * 9 + i]; break;
            case 3: v = Mg[1 * 9 + i] + Mg[2 * 9 + i]; break;
            case 4: v = Mg[3 * 9 + i] + Mg[5 * 9 + i]; break;
            case 5: v = Mg[7 * 9 + i] + Mg[8 * 9 + i]; break;
            case 6: v = Mg[1 * 9 + i] - Mg[2 * 9 + i]; break;
            case 7: v = Mg[3 * 9 + i] - Mg[5 * 9 + i]; break;
            default: v = Mg[7 * 9 + i] - Mg[8 * 9 + i]; break;
        }
        ws[528 + r * 9 + i] = v;
    } else if (t >= 160 && t < 160 + 81) {
        const int e = t - 160;
        ws[528 + 81 + e] = Minvg[e];
    } else if (t == 254) {
        ws[528 + 162] = j_b2[0];
    } else if (t == 255) {
        ws[528 + 163] = 2.0f * n_b2[0];
    }
}

__global__ __launch_bounds__(256) void mrt_main(
    const float* __restrict__ f, const float* __restrict__ W,
    float* __restrict__ out, int n2)
{
    const h2*    Wh = reinterpret_cast<const h2*>(W);
    const float* Wf = W + 528;

    long base = ((long)blockIdx.x * 256 + threadIdx.x) * 4;
    if (base + 4 > n2) base = n2 - 4;

    // ---- phase 1 (f32): tv = TM @ f ----
    float tv[9][4];
    {
        float fv[9][4];
        #pragma unroll
        for (int i = 0; i < 9; ++i) {
            const float4 u = *reinterpret_cast<const float4*>(f + (size_t)i * n2 + base);
            fv[i][0] = u.x; fv[i][1] = u.y; fv[i][2] = u.z; fv[i][3] = u.w;
        }
        #pragma unroll
        for (int r = 0; r < 9; ++r) {
            float a0 = 0.f, a1 = 0.f, a2 = 0.f, a3 = 0.f;
            #pragma unroll
            for (int i = 0; i < 9; ++i) {
                const float w = Wf[r * 9 + i];
                a0 = fmaf(w, fv[i][0], a0);
                a1 = fmaf(w, fv[i][1], a1);
                a2 = fmaf(w, fv[i][2], a2);
                a3 = fmaf(w, fv[i][3], a3);
            }
            tv[r][0] = a0; tv[r][1] = a1; tv[r][2] = a2; tv[r][3] = a3;
        }
    }

    // ---- f16 copy of tv for the MLP (2 points per h2) ----
    h2 tvh[9][2];
    #pragma unroll
    for (int r = 0; r < 9; ++r) {
        tvh[r][0].x = (_Float16)tv[r][0]; tvh[r][0].y = (_Float16)tv[r][1];
        tvh[r][1].x = (_Float16)tv[r][2]; tvh[r][1].y = (_Float16)tv[r][3];
    }

    // ---- phase 2 (packed f16): fused hidden layer ----
    h2 accj[2], accjf[2], accn[2];
    #pragma unroll
    for (int p = 0; p < 2; ++p) { accj[p] = h2splat(0.f); accjf[p] = h2splat(0.f); accn[p] = h2splat(0.f); }

    #pragma unroll 4
    for (int o = 0; o < 24; ++o) {
        const h2 s0 = Wh[o*22+0], s1 = Wh[o*22+1], s2 = Wh[o*22+2];
        const h2 s3 = Wh[o*22+3], s4 = Wh[o*22+4], s5 = Wh[o*22+5];
        const h2 a0 = Wh[o*22+6], a1 = Wh[o*22+7], a2 = Wh[o*22+8];
        const h2 b1j = Wh[o*22+9];
        const h2 u0 = Wh[o*22+10], u1 = Wh[o*22+11], u2 = Wh[o*22+12];
        const h2 u3 = Wh[o*22+13], u4 = Wh[o*22+14], u5 = Wh[o*22+15];
        const h2 v0 = Wh[o*22+16], v1 = Wh[o*22+17], v2 = Wh[o*22+18];
        const h2 b1n = Wh[o*22+19];
        const h2 w2j = Wh[o*22+20], w2n = Wh[o*22+21];
        #pragma unroll
        for (int p = 0; p < 2; ++p) {
            h2 s = h2fma(s0, tvh[0][p], b1j);
            s = h2fma(s1, tvh[1][p], s);
            s = h2fma(s2, tvh[2][p], s);
            s = h2fma(s3, tvh[3][p], s);
            s = h2fma(s4, tvh[4][p], s);
            s = h2fma(s5, tvh[5][p], s);
            h2 a = a0 * tvh[6][p];
            a = h2fma(a1, tvh[7][p], a);
            a = h2fma(a2, tvh[8][p], a);
            const h2 hs = h2relu(s + a);
            const h2 hd = h2relu(s - a);
            accj[p]  = h2fma(w2j, hs, accj[p]);
            accjf[p] = h2fma(w2j, hd, accjf[p]);

            h2 sn = h2fma(u0, tvh[0][p], b1n);
            sn = h2fma(u1, tvh[1][p], sn);
            sn = h2fma(u2, tvh[2][p], sn);
            sn = h2fma(u3, tvh[3][p], sn);
            sn = h2fma(u4, tvh[4][p], sn);
            sn = h2fma(u5, tvh[5][p], sn);
            h2 an = v0 * tvh[6][p];
            an = h2fma(v1, tvh[7][p], an);
            an = h2fma(v2, tvh[8][p], an);
            const h2 ns = h2relu(sn + an);
            const h2 nd = h2relu(sn - an);
            accn[p] = h2fma(w2n, ns + nd, accn[p]);
        }
    }

    // ---- phase 3 (f32): taus + m_post (overwrite tv in place) ----
    const float b2j = Wf[162], b2n2 = Wf[163];
    const float Cs = 1.0f / 0.7f;
    #pragma unroll
    for (int k = 0; k < 4; ++k) {
        const int p = k >> 1;
        const float aj  = (k & 1) ? (float)accj[p].y  : (float)accj[p].x;
        const float ajf = (k & 1) ? (float)accjf[p].y : (float)accjf[p].x;
        const float an  = (k & 1) ? (float)accn[p].y  : (float)accn[p].x;

        const float rt7 = __builtin_amdgcn_rcpf(0.5f + __expf(aj + b2j));
        const float rt8 = __builtin_amdgcn_rcpf(0.5f + __expf(ajf + b2j));
        const float rt6 = __builtin_amdgcn_rcpf(0.5f + __expf(an + b2n2));
        const float rrho = __builtin_amdgcn_rcpf(tv[0][k]);

        const float jx = 0.5f * (tv[3][k] + tv[6][k]);
        const float jy = 0.5f * (tv[3][k] - tv[6][k]);
        const float m3 = 0.5f * (tv[4][k] + tv[7][k]);
        const float m5 = 0.5f * (tv[4][k] - tv[7][k]);
        const float m7 = 0.5f * (tv[5][k] + tv[8][k]);
        const float m8 = 0.5f * (tv[5][k] - tv[8][k]);
        const float m4 = tv[1][k], m6 = tv[2][k];

        tv[1][k] = jx;
        tv[2][k] = jy;
        tv[3][k] = m3 - (m3 - jx * jx * rrho) * Cs;
        tv[4][k] = m4 - (m4 - jx * jy * rrho) * Cs;
        tv[5][k] = m5 - (m5 - jy * jy * rrho) * Cs;
        tv[6][k] = m6 - m6 * rt6;
        tv[7][k] = m7 - m7 * rt7;
        tv[8][k] = m8 - m8 * rt8;
    }

    // ---- phase 4 (f32): out = Minv @ m_post ----
    #pragma unroll
    for (int r = 0; r < 9; ++r) {
        float o0 = 0.f, o1 = 0.f, o2 = 0.f, o3 = 0.f;
        #pragma unroll
        for (int j = 0; j < 9; ++j) {
            const float w = Wf[81 + r * 9 + j];
            o0 = fmaf(w, tv[j][0], o0);
            o1 = fmaf(w, tv[j][1], o1);
            o2 = fmaf(w, tv[j][2], o2);
            o3 = fmaf(w, tv[j][3], o3);
        }
        const float4 vv = make_float4(o0, o1, o2, o3);
        *reinterpret_cast<float4*>(out + (size_t)r * n2 + base) = vv;
    }
}

extern "C" void kernel_launch(void* const* d_in, const int* in_sizes, int n_in,
                              void* d_out, int out_size, void* d_ws, size_t ws_size,
                              hipStream_t stream) {
    const float* f    = (const float*)d_in[0];
    const float* j_w1 = (const float*)d_in[1];
    const float* j_b1 = (const float*)d_in[2];
    const float* j_w2 = (const float*)d_in[3];
    const float* j_b2 = (const float*)d_in[4];
    const float* n_w1 = (const float*)d_in[5];
    const float* n_b1 = (const float*)d_in[6];
    const float* n_w2 = (const float*)d_in[7];
    const float* n_b2 = (const float*)d_in[8];
    const float* Mg   = (const float*)d_in[9];
    const float* Minv = (const float*)d_in[10];
    float* out = (float*)d_out;
    float* ws  = (float*)d_ws;

    const int n2 = in_sizes[0] / 9;
    const int pts_per_block = 256 * 4;
    const int grid = (n2 + pts_per_block - 1) / pts_per_block;

    prep_kernel<<<1, 256, 0, stream>>>(j_w1, j_b1, j_w2, j_b2,
                                       n_w1, n_b1, n_w2, n_b2, Mg, Minv, ws);
    mrt_main<<<grid, 256, 0, stream>>>(f, ws, out, n2);
}